// Round 2
// baseline (260.750 us; speedup 1.0000x reference)
//
#include <hip/hip_runtime.h>
#include <hip/hip_bf16.h>

#define N_NODES 20000
#define N_EDGES 300000
#define FDIM    268
#define EPS     1e-3f

// ---------------- CSR build ----------------

__global__ void count_kernel(const int* __restrict__ col, int* __restrict__ counts) {
    int e = blockIdx.x * blockDim.x + threadIdx.x;
    if (e < N_EDGES) atomicAdd(&counts[col[e]], 1);
}

// single block, 256 threads: exclusive scan of counts -> offs, cursor; also dis = rsqrt(deg+1)
__global__ void scan_kernel(const int* __restrict__ counts, int* __restrict__ offs,
                            int* __restrict__ cursor, float* __restrict__ dis) {
    __shared__ int sums[256];
    const int T = 256;
    int t = threadIdx.x;
    const int chunk = (N_NODES + T - 1) / T;   // 79
    int lo = t * chunk;
    int hi = lo + chunk; if (hi > N_NODES) hi = N_NODES;
    int s = 0;
    for (int i = lo; i < hi; ++i) s += counts[i];
    sums[t] = s;
    __syncthreads();
    if (t == 0) {
        int run = 0;
        for (int k = 0; k < T; ++k) { int v = sums[k]; sums[k] = run; run += v; }
    }
    __syncthreads();
    int run = sums[t];
    for (int i = lo; i < hi; ++i) {
        offs[i] = run;
        cursor[i] = run;
        run += counts[i];
        dis[i] = rsqrtf((float)(counts[i] + 1));   // +1 self-loop; deg >= 1 always
    }
    if (t == T - 1) offs[N_NODES] = run;
}

__global__ void fill_kernel(const int* __restrict__ row, const int* __restrict__ col,
                            int* __restrict__ cursor, int* __restrict__ esrc) {
    int e = blockIdx.x * blockDim.x + threadIdx.x;
    if (e < N_EDGES) {
        int c = col[e];
        int p = atomicAdd(&cursor[c], 1);
        esrc[p] = row[e];
    }
}

// ---------------- GEMM: h1 = x @ W1   [M,K]x[K,N], fp32 ----------------
#define TM 128
#define TN 64
#define BKK 16

__global__ __launch_bounds__(256) void gemm_xw(const float* __restrict__ A,
                                               const float* __restrict__ B,
                                               float* __restrict__ C,
                                               int M, int N, int K) {
    __shared__ float As[BKK][TM + 4];
    __shared__ float Bs[BKK][TN + 4];
    const int tid = threadIdx.x;
    const int tx = tid & 15;   // -> n
    const int ty = tid >> 4;   // -> m
    const int m0 = blockIdx.x * TM;
    const int n0 = blockIdx.y * TN;

    float acc[8][4];
#pragma unroll
    for (int i = 0; i < 8; ++i)
#pragma unroll
        for (int j = 0; j < 4; ++j) acc[i][j] = 0.f;

    const int la_k = tid & 15;        // k for A load
    const int la_m = tid >> 4;        // m base (step 16)
    const int lb_k = tid >> 4;        // k for B load
    const int lb_n = (tid & 15) * 4;  // n base (4 consecutive)

    for (int k0 = 0; k0 < K; k0 += BKK) {
#pragma unroll
        for (int j = 0; j < 8; ++j) {
            int m = la_m + j * 16;
            int gm = m0 + m, gk = k0 + la_k;
            As[la_k][m] = (gm < M && gk < K) ? A[(size_t)gm * K + gk] : 0.f;
        }
#pragma unroll
        for (int j = 0; j < 4; ++j) {
            int n = lb_n + j;
            int gk = k0 + lb_k, gn = n0 + n;
            Bs[lb_k][n] = (gk < K && gn < N) ? B[(size_t)gk * N + gn] : 0.f;
        }
        __syncthreads();
#pragma unroll
        for (int kk = 0; kk < BKK; ++kk) {
            float a[8], b[4];
#pragma unroll
            for (int i = 0; i < 8; ++i) a[i] = As[kk][ty * 8 + i];
#pragma unroll
            for (int j = 0; j < 4; ++j) b[j] = Bs[kk][tx * 4 + j];
#pragma unroll
            for (int i = 0; i < 8; ++i)
#pragma unroll
                for (int j = 0; j < 4; ++j) acc[i][j] += a[i] * b[j];
        }
        __syncthreads();
    }
#pragma unroll
    for (int i = 0; i < 8; ++i) {
        int gm = m0 + ty * 8 + i;
        if (gm >= M) continue;
#pragma unroll
        for (int j = 0; j < 4; ++j) {
            int gn = n0 + tx * 4 + j;
            if (gn < N) C[(size_t)gm * N + gn] = acc[i][j];
        }
    }
}

// ---------------- agg1: pull-aggregate + bias + relu + bn + relu + dot(W2) -> z ----------------
// one wave (64 lanes) per node; lane covers features f = 4*lane (+ 256+4*lane for lane<3)
__global__ __launch_bounds__(256) void agg1_kernel(const float* __restrict__ h1,
                                                   const int* __restrict__ offs,
                                                   const int* __restrict__ esrc,
                                                   const float* __restrict__ dis,
                                                   const float* __restrict__ b1,
                                                   const float* __restrict__ g1,
                                                   const float* __restrict__ beta1,
                                                   const float* __restrict__ rm1,
                                                   const float* __restrict__ rv1,
                                                   const float* __restrict__ W2,
                                                   float* __restrict__ z) {
    int wave = blockIdx.x * 4 + (threadIdx.x >> 6);
    int lane = threadIdx.x & 63;
    if (wave >= N_NODES) return;
    const int i = wave;

    float a0x = 0.f, a0y = 0.f, a0z = 0.f, a0w = 0.f;
    float a1x = 0.f, a1y = 0.f, a1z = 0.f, a1w = 0.f;

    int s = offs[i], e = offs[i + 1];
    for (int p = s; p < e; ++p) {
        int src = esrc[p];
        float w = dis[src];
        const float4* hr = reinterpret_cast<const float4*>(h1 + (size_t)src * FDIM);
        float4 v0 = hr[lane];
        a0x += w * v0.x; a0y += w * v0.y; a0z += w * v0.z; a0w += w * v0.w;
        if (lane < 3) {
            float4 v1 = hr[64 + lane];
            a1x += w * v1.x; a1y += w * v1.y; a1z += w * v1.z; a1w += w * v1.w;
        }
    }
    float di = dis[i];
    {   // self loop: dis[i]^2 * h1[i]  (outer di applied below)
        const float4* hr = reinterpret_cast<const float4*>(h1 + (size_t)i * FDIM);
        float4 v0 = hr[lane];
        a0x += di * v0.x; a0y += di * v0.y; a0z += di * v0.z; a0w += di * v0.w;
        if (lane < 3) {
            float4 v1 = hr[64 + lane];
            a1x += di * v1.x; a1y += di * v1.y; a1z += di * v1.z; a1w += di * v1.w;
        }
    }

    const float4* b1v = reinterpret_cast<const float4*>(b1);
    const float4* g1v = reinterpret_cast<const float4*>(g1);
    const float4* be1v = reinterpret_cast<const float4*>(beta1);
    const float4* rm1v = reinterpret_cast<const float4*>(rm1);
    const float4* rv1v = reinterpret_cast<const float4*>(rv1);
    const float4* w2v = reinterpret_cast<const float4*>(W2);

    float zp = 0.f;
    {
        float4 bb = b1v[lane], gg = g1v[lane], be = be1v[lane], rm = rm1v[lane], rv = rv1v[lane], ww = w2v[lane];
        float v;
        v = fmaxf(di * a0x + bb.x, 0.f); v = fmaxf((v - rm.x) * rsqrtf(rv.x + EPS) * gg.x + be.x, 0.f); zp += v * ww.x;
        v = fmaxf(di * a0y + bb.y, 0.f); v = fmaxf((v - rm.y) * rsqrtf(rv.y + EPS) * gg.y + be.y, 0.f); zp += v * ww.y;
        v = fmaxf(di * a0z + bb.z, 0.f); v = fmaxf((v - rm.z) * rsqrtf(rv.z + EPS) * gg.z + be.z, 0.f); zp += v * ww.z;
        v = fmaxf(di * a0w + bb.w, 0.f); v = fmaxf((v - rm.w) * rsqrtf(rv.w + EPS) * gg.w + be.w, 0.f); zp += v * ww.w;
    }
    if (lane < 3) {
        float4 bb = b1v[64 + lane], gg = g1v[64 + lane], be = be1v[64 + lane], rm = rm1v[64 + lane], rv = rv1v[64 + lane], ww = w2v[64 + lane];
        float v;
        v = fmaxf(di * a1x + bb.x, 0.f); v = fmaxf((v - rm.x) * rsqrtf(rv.x + EPS) * gg.x + be.x, 0.f); zp += v * ww.x;
        v = fmaxf(di * a1y + bb.y, 0.f); v = fmaxf((v - rm.y) * rsqrtf(rv.y + EPS) * gg.y + be.y, 0.f); zp += v * ww.y;
        v = fmaxf(di * a1z + bb.z, 0.f); v = fmaxf((v - rm.z) * rsqrtf(rv.z + EPS) * gg.z + be.z, 0.f); zp += v * ww.z;
        v = fmaxf(di * a1w + bb.w, 0.f); v = fmaxf((v - rm.w) * rsqrtf(rv.w + EPS) * gg.w + be.w, 0.f); zp += v * ww.w;
    }
#pragma unroll
    for (int off = 32; off > 0; off >>= 1) zp += __shfl_xor(zp, off);
    if (lane == 0) z[i] = zp;
}

// ---------------- agg2: pull-aggregate z + bias + bn + relu + sigmoid -> out ----------------
__global__ void agg2_kernel(const float* __restrict__ z,
                            const int* __restrict__ offs,
                            const int* __restrict__ esrc,
                            const float* __restrict__ dis,
                            const float* __restrict__ b2,
                            const float* __restrict__ g2,
                            const float* __restrict__ beta2,
                            const float* __restrict__ rm2,
                            const float* __restrict__ rv2,
                            float* __restrict__ out) {
    int i = blockIdx.x * blockDim.x + threadIdx.x;
    if (i >= N_NODES) return;
    int s = offs[i], e = offs[i + 1];
    float acc = 0.f;
    for (int p = s; p < e; ++p) {
        int src = esrc[p];
        acc += dis[src] * z[src];
    }
    float di = dis[i];
    acc += di * z[i];                 // self loop
    float pre = di * acc + b2[0];
    float v = (pre - rm2[0]) * rsqrtf(rv2[0] + EPS) * g2[0] + beta2[0];
    v = fmaxf(v, 0.f);
    out[i] = 1.f / (1.f + expf(-v));
}

// ---------------- launcher ----------------
extern "C" void kernel_launch(void* const* d_in, const int* in_sizes, int n_in,
                              void* d_out, int out_size, void* d_ws, size_t ws_size,
                              hipStream_t stream) {
    const float* x     = (const float*)d_in[0];
    const int*   ei    = (const int*)d_in[1];     // [2, E]: row = ei, col = ei + E
    const float* W1    = (const float*)d_in[2];
    const float* b1    = (const float*)d_in[3];
    const float* g1    = (const float*)d_in[4];
    const float* beta1 = (const float*)d_in[5];
    const float* rm1   = (const float*)d_in[6];
    const float* rv1   = (const float*)d_in[7];
    const float* W2    = (const float*)d_in[8];
    const float* b2    = (const float*)d_in[9];
    const float* g2    = (const float*)d_in[10];
    const float* beta2 = (const float*)d_in[11];
    const float* rm2   = (const float*)d_in[12];
    const float* rv2   = (const float*)d_in[13];
    float* out = (float*)d_out;

    // workspace layout
    float* h1    = (float*)d_ws;                    // N*F floats
    float* z     = h1 + (size_t)N_NODES * FDIM;     // N
    float* dis   = z + N_NODES;                     // N
    int*   counts = (int*)(dis + N_NODES);          // N
    int*   offs   = counts + N_NODES;               // N+1
    int*   cursor = offs + N_NODES + 1;             // N
    int*   esrc   = cursor + N_NODES;               // E

    const int* row = ei;
    const int* col = ei + N_EDGES;

    hipMemsetAsync(counts, 0, N_NODES * sizeof(int), stream);

    int eb = (N_EDGES + 255) / 256;
    count_kernel<<<eb, 256, 0, stream>>>(col, counts);
    scan_kernel<<<1, 256, 0, stream>>>(counts, offs, cursor, dis);
    fill_kernel<<<eb, 256, 0, stream>>>(row, col, cursor, esrc);

    dim3 ggrid((N_NODES + TM - 1) / TM, (FDIM + TN - 1) / TN);
    gemm_xw<<<ggrid, 256, 0, stream>>>(x, W1, h1, N_NODES, FDIM, FDIM);

    agg1_kernel<<<(N_NODES + 3) / 4, 256, 0, stream>>>(h1, offs, esrc, dis,
                                                       b1, g1, beta1, rm1, rv1, W2, z);
    agg2_kernel<<<(N_NODES + 255) / 256, 256, 0, stream>>>(z, offs, esrc, dis,
                                                           b2, g2, beta2, rm2, rv2, out);
}

// Round 3
// 191.977 us; speedup vs baseline: 1.3582x; 1.3582x over previous
//
#include <hip/hip_runtime.h>
#include <hip/hip_bf16.h>

#define N_NODES 20000
#define N_EDGES 300000
#define FDIM    268
#define KPAD    288   // K padded to 9*32 for mfma K-loop
#define NPAD    288   // N padded to 9*32
#define HPAD    272   // h1 row stride in bf16 (34 slots * 8)
#define EPS     1e-3f

typedef __attribute__((ext_vector_type(8))) short short8;
typedef __attribute__((ext_vector_type(4))) float f32x4;
typedef __attribute__((ext_vector_type(8))) unsigned short ushort8;

__device__ inline short f2bf(float f) {
    __hip_bfloat16 b = __float2bfloat16(f);   // RNE
    return *reinterpret_cast<short*>(&b);
}
__device__ inline float bf2f(unsigned short u) {
    return __uint_as_float(((unsigned int)u) << 16);
}

// ---------------- CSR build ----------------

__global__ void count_kernel(const int* __restrict__ col, int* __restrict__ counts) {
    int e = blockIdx.x * blockDim.x + threadIdx.x;
    if (e < N_EDGES) atomicAdd(&counts[col[e]], 1);
}

// single block, 1024 threads: exclusive scan of counts -> offs, cursor; dis = rsqrt(deg+1)
__global__ __launch_bounds__(1024) void scan_kernel(const int* __restrict__ counts,
                                                    int* __restrict__ offs,
                                                    int* __restrict__ cursor,
                                                    float* __restrict__ dis) {
    __shared__ int sums[1024];
    const int T = 1024;
    int t = threadIdx.x;
    const int chunk = (N_NODES + T - 1) / T;   // 20
    int lo = t * chunk;
    int hi = lo + chunk; if (hi > N_NODES) hi = N_NODES;
    int s = 0;
    for (int i = lo; i < hi; ++i) s += counts[i];
    sums[t] = s;
    __syncthreads();
    if (t == 0) {
        int run = 0;
        for (int k = 0; k < T; ++k) { int v = sums[k]; sums[k] = run; run += v; }
    }
    __syncthreads();
    int run = sums[t];
    for (int i = lo; i < hi; ++i) {
        offs[i] = run;
        cursor[i] = run;
        run += counts[i];
        dis[i] = rsqrtf((float)(counts[i] + 1));   // +1 self-loop
    }
    if (t == T - 1) offs[N_NODES] = run;
}

__global__ void fill_kernel(const int* __restrict__ row, const int* __restrict__ col,
                            int* __restrict__ cursor, int* __restrict__ esrc) {
    int e = blockIdx.x * blockDim.x + threadIdx.x;
    if (e < N_EDGES) {
        int c = col[e];
        int p = atomicAdd(&cursor[c], 1);
        esrc[p] = row[e];
    }
}

// ---------------- W1 -> W1^T bf16, zero-padded [NPAD][KPAD] ----------------
__global__ void conv_w(const float* __restrict__ W1, unsigned short* __restrict__ wt) {
    int idx = blockIdx.x * blockDim.x + threadIdx.x;
    if (idx >= NPAD * KPAD) return;
    int n = idx / KPAD, k = idx - n * KPAD;
    float v = (n < FDIM && k < FDIM) ? W1[(size_t)k * FDIM + n] : 0.f;
    wt[idx] = (unsigned short)f2bf(v);
}

// ---------------- GEMM: h1b = bf16(x) @ bf16(W1), output bf16 [N_NODES][HPAD] ----------------
// wave computes 32x32 via 2x2 mfma_f32_16x16x32_bf16 frags; A read direct from fp32 x.
__global__ __launch_bounds__(256) void gemm_mfma(const float* __restrict__ x,
                                                 const unsigned short* __restrict__ wt,
                                                 unsigned short* __restrict__ h1b) {
    int wid = blockIdx.x * 4 + (threadIdx.x >> 6);
    int m_idx = wid / 9;                  // n fastest: 9 n-waves share the A m-strip
    int n_idx = wid - m_idx * 9;
    if (m_idx >= N_NODES / 32) return;
    int lane = threadIdx.x & 63;
    int lrow = lane & 15;
    int lkg  = lane >> 4;                 // k-group 0..3
    int m0 = m_idx * 32, n0 = n_idx * 32;

    f32x4 acc[2][2];
#pragma unroll
    for (int a = 0; a < 2; ++a)
#pragma unroll
        for (int b = 0; b < 2; ++b) acc[a][b] = (f32x4){0.f, 0.f, 0.f, 0.f};

    const float* xr0 = x + (size_t)(m0 + lrow) * FDIM;
    const float* xr1 = x + (size_t)(m0 + 16 + lrow) * FDIM;

#pragma unroll
    for (int k0 = 0; k0 < KPAD; k0 += 32) {
        const int kb = k0 + lkg * 8;
        short8 a0, a1;
#pragma unroll
        for (int j = 0; j < 8; ++j) {
            int k = kb + j;                         // k0 compile-time -> mask folds away
            float v0 = (k < FDIM) ? xr0[k] : 0.f;
            float v1 = (k < FDIM) ? xr1[k] : 0.f;
            a0[j] = f2bf(v0);
            a1[j] = f2bf(v1);
        }
        short8 b0 = *reinterpret_cast<const short8*>(wt + (size_t)(n0 + lrow) * KPAD + kb);
        short8 b1 = *reinterpret_cast<const short8*>(wt + (size_t)(n0 + 16 + lrow) * KPAD + kb);
        acc[0][0] = __builtin_amdgcn_mfma_f32_16x16x32_bf16(a0, b0, acc[0][0], 0, 0, 0);
        acc[0][1] = __builtin_amdgcn_mfma_f32_16x16x32_bf16(a0, b1, acc[0][1], 0, 0, 0);
        acc[1][0] = __builtin_amdgcn_mfma_f32_16x16x32_bf16(a1, b0, acc[1][0], 0, 0, 0);
        acc[1][1] = __builtin_amdgcn_mfma_f32_16x16x32_bf16(a1, b1, acc[1][1], 0, 0, 0);
    }

    // C/D layout: col = lane&15, row = (lane>>4)*4 + reg   [m89-verified]
#pragma unroll
    for (int mi = 0; mi < 2; ++mi)
#pragma unroll
        for (int ni = 0; ni < 2; ++ni) {
            int colg = n0 + ni * 16 + lrow;
            if (colg < HPAD) {
#pragma unroll
                for (int r = 0; r < 4; ++r) {
                    int rowg = m0 + mi * 16 + lkg * 4 + r;
                    h1b[(size_t)rowg * HPAD + colg] = (unsigned short)f2bf(acc[mi][ni][r]);
                }
            }
        }
}

// ---------------- agg1: pull-aggregate bf16 h1 + bias+relu+bn+relu + dot(W2) -> z ----------------
// one wave per node; half-wave (32 lanes x 16B) per edge, 2 edges in flight.
__global__ __launch_bounds__(256) void agg1_kernel(const unsigned short* __restrict__ h1b,
                                                   const int* __restrict__ offs,
                                                   const int* __restrict__ esrc,
                                                   const float* __restrict__ dis,
                                                   const float* __restrict__ b1,
                                                   const float* __restrict__ g1,
                                                   const float* __restrict__ beta1,
                                                   const float* __restrict__ rm1,
                                                   const float* __restrict__ rv1,
                                                   const float* __restrict__ W2,
                                                   float* __restrict__ z) {
    int wave = blockIdx.x * 4 + (threadIdx.x >> 6);
    if (wave >= N_NODES) return;
    int lane = threadIdx.x & 63;
    int h  = lane >> 5;       // half 0/1
    int sl = lane & 31;       // slot 0..31 (features sl*8..sl*8+7)
    const int i = wave;

    float a[8]  = {0.f, 0.f, 0.f, 0.f, 0.f, 0.f, 0.f, 0.f};
    float ta[8] = {0.f, 0.f, 0.f, 0.f, 0.f, 0.f, 0.f, 0.f};  // tail slots 32/33 (lanes sl<2)

    int s = offs[i], e = offs[i + 1];
    for (int p = s + h; p < e; p += 2) {
        int src = esrc[p];
        float w = dis[src];
        const ushort8* hr = reinterpret_cast<const ushort8*>(h1b + (size_t)src * HPAD);
        ushort8 v = hr[sl];
#pragma unroll
        for (int j = 0; j < 8; ++j) a[j] += w * bf2f(v[j]);
        if (sl < 2) {
            ushort8 vt = hr[32 + sl];
#pragma unroll
            for (int j = 0; j < 8; ++j) ta[j] += w * bf2f(vt[j]);
        }
    }
    float di = dis[i];
    if (h == 0) {   // self-loop once (halves merged below)
        const ushort8* hr = reinterpret_cast<const ushort8*>(h1b + (size_t)i * HPAD);
        ushort8 v = hr[sl];
#pragma unroll
        for (int j = 0; j < 8; ++j) a[j] += di * bf2f(v[j]);
        if (sl < 2) {
            ushort8 vt = hr[32 + sl];
#pragma unroll
            for (int j = 0; j < 8; ++j) ta[j] += di * bf2f(vt[j]);
        }
    }
    // merge halves
#pragma unroll
    for (int j = 0; j < 8; ++j) a[j]  += __shfl_xor(a[j], 32);
#pragma unroll
    for (int j = 0; j < 8; ++j) ta[j] += __shfl_xor(ta[j], 32);

    float zp = 0.f;
    if (h == 0) {
        int f0 = sl * 8;
#pragma unroll
        for (int j = 0; j < 8; ++j) {
            int f = f0 + j;
            float v = fmaxf(di * a[j] + b1[f], 0.f);
            v = fmaxf((v - rm1[f]) * rsqrtf(rv1[f] + EPS) * g1[f] + beta1[f], 0.f);
            zp += v * W2[f];
        }
        if (sl < 2) {
            int ft0 = 256 + sl * 8;
#pragma unroll
            for (int j = 0; j < 8; ++j) {
                int f = ft0 + j;
                if (f < FDIM) {
                    float v = fmaxf(di * ta[j] + b1[f], 0.f);
                    v = fmaxf((v - rm1[f]) * rsqrtf(rv1[f] + EPS) * g1[f] + beta1[f], 0.f);
                    zp += v * W2[f];
                }
            }
        }
    }
#pragma unroll
    for (int off = 32; off > 0; off >>= 1) zp += __shfl_xor(zp, off);
    if (lane == 0) z[i] = zp;
}

// ---------------- agg2: pull-aggregate z + bias + bn + relu + sigmoid -> out ----------------
__global__ void agg2_kernel(const float* __restrict__ z,
                            const int* __restrict__ offs,
                            const int* __restrict__ esrc,
                            const float* __restrict__ dis,
                            const float* __restrict__ b2,
                            const float* __restrict__ g2,
                            const float* __restrict__ beta2,
                            const float* __restrict__ rm2,
                            const float* __restrict__ rv2,
                            float* __restrict__ out) {
    int i = blockIdx.x * blockDim.x + threadIdx.x;
    if (i >= N_NODES) return;
    int s = offs[i], e = offs[i + 1];
    float acc = 0.f;
    for (int p = s; p < e; ++p) {
        int src = esrc[p];
        acc += dis[src] * z[src];
    }
    float di = dis[i];
    acc += di * z[i];                 // self loop
    float pre = di * acc + b2[0];
    float v = (pre - rm2[0]) * rsqrtf(rv2[0] + EPS) * g2[0] + beta2[0];
    v = fmaxf(v, 0.f);
    out[i] = 1.f / (1.f + expf(-v));
}

// ---------------- launcher ----------------
extern "C" void kernel_launch(void* const* d_in, const int* in_sizes, int n_in,
                              void* d_out, int out_size, void* d_ws, size_t ws_size,
                              hipStream_t stream) {
    const float* x     = (const float*)d_in[0];
    const int*   ei    = (const int*)d_in[1];     // [2, E]: row = ei, col = ei + E
    const float* W1    = (const float*)d_in[2];
    const float* b1    = (const float*)d_in[3];
    const float* g1    = (const float*)d_in[4];
    const float* beta1 = (const float*)d_in[5];
    const float* rm1   = (const float*)d_in[6];
    const float* rv1   = (const float*)d_in[7];
    const float* W2    = (const float*)d_in[8];
    const float* b2    = (const float*)d_in[9];
    const float* g2    = (const float*)d_in[10];
    const float* beta2 = (const float*)d_in[11];
    const float* rm2   = (const float*)d_in[12];
    const float* rv2   = (const float*)d_in[13];
    float* out = (float*)d_out;

    // workspace layout (~12.8 MB)
    unsigned short* wt  = (unsigned short*)d_ws;            // NPAD*KPAD
    unsigned short* h1b = wt + (size_t)NPAD * KPAD;         // N_NODES*HPAD
    float* z    = (float*)(h1b + (size_t)N_NODES * HPAD);
    float* dis  = z + N_NODES;
    int* counts = (int*)(dis + N_NODES);
    int* offs   = counts + N_NODES;
    int* cursor = offs + N_NODES + 1;
    int* esrc   = cursor + N_NODES;

    const int* row = ei;
    const int* col = ei + N_EDGES;

    hipMemsetAsync(counts, 0, N_NODES * sizeof(int), stream);

    int eb = (N_EDGES + 255) / 256;
    count_kernel<<<eb, 256, 0, stream>>>(col, counts);
    scan_kernel<<<1, 1024, 0, stream>>>(counts, offs, cursor, dis);
    fill_kernel<<<eb, 256, 0, stream>>>(row, col, cursor, esrc);

    conv_w<<<(NPAD * KPAD + 255) / 256, 256, 0, stream>>>(W1, wt);

    int nwaves = (N_NODES / 32) * 9;                 // 5625
    gemm_mfma<<<(nwaves + 3) / 4, 256, 0, stream>>>(x, wt, h1b);

    agg1_kernel<<<(N_NODES + 3) / 4, 256, 0, stream>>>(h1b, offs, esrc, dis,
                                                       b1, g1, beta1, rm1, rv1, W2, z);
    agg2_kernel<<<(N_NODES + 255) / 256, 256, 0, stream>>>(z, offs, esrc, dis,
                                                           b2, g2, beta2, rm2, rv2, out);
}

// Round 4
// 176.844 us; speedup vs baseline: 1.4745x; 1.0856x over previous
//
#include <hip/hip_runtime.h>
#include <hip/hip_bf16.h>

#define N_NODES 20000
#define N_EDGES 300000
#define FDIM    268
#define KPAD    288   // K padded to 9*32 for mfma K-loop
#define NPAD    288   // N padded to 9*32
#define HPAD    272   // h1 row stride in bf16 (34 slots * 8)
#define HSLOTS  34    // HPAD/8
#define EPS     1e-3f

typedef __attribute__((ext_vector_type(8))) short short8;
typedef __attribute__((ext_vector_type(4))) float f32x4;
typedef __attribute__((ext_vector_type(8))) unsigned short ushort8;

__device__ inline short f2bf(float f) {
    __hip_bfloat16 b = __float2bfloat16(f);   // RNE
    return *reinterpret_cast<short*>(&b);
}
__device__ inline float bf2f(unsigned short u) {
    return __uint_as_float(((unsigned int)u) << 16);
}

// ---------------- CSR build ----------------

__global__ void count_kernel(const int* __restrict__ col, int* __restrict__ counts) {
    int e = blockIdx.x * blockDim.x + threadIdx.x;
    if (e < N_EDGES) atomicAdd(&counts[col[e]], 1);
}

// single block, 1024 threads: exclusive scan of counts -> offs, cursor; dis = rsqrt(deg+1)
__global__ __launch_bounds__(1024) void scan_kernel(const int* __restrict__ counts,
                                                    int* __restrict__ offs,
                                                    int* __restrict__ cursor,
                                                    float* __restrict__ dis) {
    __shared__ int sums[1024];
    const int T = 1024;
    int t = threadIdx.x;
    const int chunk = (N_NODES + T - 1) / T;   // 20
    int lo = t * chunk;
    int hi = lo + chunk; if (hi > N_NODES) hi = N_NODES;
    int s = 0;
    for (int i = lo; i < hi; ++i) s += counts[i];
    sums[t] = s;
    __syncthreads();
    if (t == 0) {
        int run = 0;
        for (int k = 0; k < T; ++k) { int v = sums[k]; sums[k] = run; run += v; }
    }
    __syncthreads();
    int run = sums[t];
    for (int i = lo; i < hi; ++i) {
        offs[i] = run;
        cursor[i] = run;
        run += counts[i];
        dis[i] = rsqrtf((float)(counts[i] + 1));   // +1 self-loop
    }
    if (t == T - 1) offs[N_NODES] = run;
}

__global__ void fill_kernel(const int* __restrict__ row, const int* __restrict__ col,
                            int* __restrict__ cursor, int* __restrict__ esrc) {
    int e = blockIdx.x * blockDim.x + threadIdx.x;
    if (e < N_EDGES) {
        int c = col[e];
        int p = atomicAdd(&cursor[c], 1);
        esrc[p] = row[e];
    }
}

// ---------------- W1 -> W1^T bf16, zero-padded [NPAD][KPAD] ----------------
__global__ void conv_w(const float* __restrict__ W1, unsigned short* __restrict__ wt) {
    int idx = blockIdx.x * blockDim.x + threadIdx.x;
    if (idx >= NPAD * KPAD) return;
    int n = idx / KPAD, k = idx - n * KPAD;
    float v = (n < FDIM && k < FDIM) ? W1[(size_t)k * FDIM + n] : 0.f;
    wt[idx] = (unsigned short)f2bf(v);
}

// ---------------- GEMM: h1b = bf16(x) @ bf16(W1), output bf16 [N_NODES][HPAD] ----------------
// wave computes 32x32 via 2x2 mfma_f32_16x16x32_bf16 frags; A read direct from fp32 x.
__global__ __launch_bounds__(256) void gemm_mfma(const float* __restrict__ x,
                                                 const unsigned short* __restrict__ wt,
                                                 unsigned short* __restrict__ h1b) {
    int wid = blockIdx.x * 4 + (threadIdx.x >> 6);
    int m_idx = wid / 9;                  // n fastest: 9 n-waves share the A m-strip
    int n_idx = wid - m_idx * 9;
    if (m_idx >= N_NODES / 32) return;
    int lane = threadIdx.x & 63;
    int lrow = lane & 15;
    int lkg  = lane >> 4;                 // k-group 0..3
    int m0 = m_idx * 32, n0 = n_idx * 32;

    f32x4 acc[2][2];
#pragma unroll
    for (int a = 0; a < 2; ++a)
#pragma unroll
        for (int b = 0; b < 2; ++b) acc[a][b] = (f32x4){0.f, 0.f, 0.f, 0.f};

    const float* xr0 = x + (size_t)(m0 + lrow) * FDIM;
    const float* xr1 = x + (size_t)(m0 + 16 + lrow) * FDIM;

#pragma unroll
    for (int k0 = 0; k0 < KPAD; k0 += 32) {
        const int kb = k0 + lkg * 8;
        short8 a0, a1;
#pragma unroll
        for (int j = 0; j < 8; ++j) {
            int k = kb + j;                         // k0 compile-time -> mask folds away
            float v0 = (k < FDIM) ? xr0[k] : 0.f;
            float v1 = (k < FDIM) ? xr1[k] : 0.f;
            a0[j] = f2bf(v0);
            a1[j] = f2bf(v1);
        }
        short8 b0 = *reinterpret_cast<const short8*>(wt + (size_t)(n0 + lrow) * KPAD + kb);
        short8 b1 = *reinterpret_cast<const short8*>(wt + (size_t)(n0 + 16 + lrow) * KPAD + kb);
        acc[0][0] = __builtin_amdgcn_mfma_f32_16x16x32_bf16(a0, b0, acc[0][0], 0, 0, 0);
        acc[0][1] = __builtin_amdgcn_mfma_f32_16x16x32_bf16(a0, b1, acc[0][1], 0, 0, 0);
        acc[1][0] = __builtin_amdgcn_mfma_f32_16x16x32_bf16(a1, b0, acc[1][0], 0, 0, 0);
        acc[1][1] = __builtin_amdgcn_mfma_f32_16x16x32_bf16(a1, b1, acc[1][1], 0, 0, 0);
    }

    // C/D layout: col = lane&15, row = (lane>>4)*4 + reg   [m89-verified]
#pragma unroll
    for (int mi = 0; mi < 2; ++mi)
#pragma unroll
        for (int ni = 0; ni < 2; ++ni) {
            int colg = n0 + ni * 16 + lrow;
            if (colg < HPAD) {
#pragma unroll
                for (int r = 0; r < 4; ++r) {
                    int rowg = m0 + mi * 16 + lkg * 4 + r;
                    h1b[(size_t)rowg * HPAD + colg] = (unsigned short)f2bf(acc[mi][ni][r]);
                }
            }
        }
}

// ---------------- agg1: pull-aggregate bf16 h1 + bias+relu+bn+relu + dot(W2) -> z ----------------
// one wave per node. Neighbor list pre-loaded coalesced (lane l -> edge l), (src,w)
// broadcast via shfl; half-wave (32 lanes x 16B) per row, 4 rows in flight per half.
__global__ __launch_bounds__(256) void agg1_kernel(const unsigned short* __restrict__ h1b,
                                                   const int* __restrict__ offs,
                                                   const int* __restrict__ esrc,
                                                   const float* __restrict__ dis,
                                                   const float* __restrict__ b1,
                                                   const float* __restrict__ g1,
                                                   const float* __restrict__ beta1,
                                                   const float* __restrict__ rm1,
                                                   const float* __restrict__ rv1,
                                                   const float* __restrict__ W2,
                                                   float* __restrict__ z) {
    int wave = blockIdx.x * 4 + (threadIdx.x >> 6);
    if (wave >= N_NODES) return;
    int lane = threadIdx.x & 63;
    int h  = lane >> 5;       // half 0/1
    int sl = lane & 31;       // slot 0..31 (features sl*8..sl*8+7)
    const int i = wave;

    float a[8]  = {0.f, 0.f, 0.f, 0.f, 0.f, 0.f, 0.f, 0.f};
    float ta[8] = {0.f, 0.f, 0.f, 0.f, 0.f, 0.f, 0.f, 0.f};  // tail slots 32/33 (lanes sl<2)

    const ushort8* base = reinterpret_cast<const ushort8*>(h1b);
    const int s = offs[i], e = offs[i + 1];
    const int deg = e - s;

    // chunks of <=64 edges (deg > 64 is astronomically rare but handled)
    for (int c0 = 0; c0 < deg; c0 += 64) {
        int cnt = deg - c0; if (cnt > 64) cnt = 64;
        int   lsrc = 0;
        float lw   = 0.f;
        if (lane < cnt) {
            lsrc = esrc[s + c0 + lane];    // coalesced
            lw   = dis[lsrc];
        }
        int p = h;
        // 4 rows in flight per half-wave (8 per wave)
        for (; p + 6 < cnt; p += 8) {
            int   s0 = __shfl(lsrc, p),     s1 = __shfl(lsrc, p + 2);
            int   s2 = __shfl(lsrc, p + 4), s3 = __shfl(lsrc, p + 6);
            float w0 = __shfl(lw, p),       w1 = __shfl(lw, p + 2);
            float w2 = __shfl(lw, p + 4),   w3 = __shfl(lw, p + 6);
            const ushort8* r0 = base + (size_t)s0 * HSLOTS;
            const ushort8* r1 = base + (size_t)s1 * HSLOTS;
            const ushort8* r2 = base + (size_t)s2 * HSLOTS;
            const ushort8* r3 = base + (size_t)s3 * HSLOTS;
            ushort8 v0 = r0[sl], v1 = r1[sl], v2 = r2[sl], v3 = r3[sl];
#pragma unroll
            for (int j = 0; j < 8; ++j)
                a[j] += w0 * bf2f(v0[j]) + w1 * bf2f(v1[j]) + w2 * bf2f(v2[j]) + w3 * bf2f(v3[j]);
            if (sl < 2) {
                ushort8 t0 = r0[32 + sl], t1 = r1[32 + sl], t2 = r2[32 + sl], t3 = r3[32 + sl];
#pragma unroll
                for (int j = 0; j < 8; ++j)
                    ta[j] += w0 * bf2f(t0[j]) + w1 * bf2f(t1[j]) + w2 * bf2f(t2[j]) + w3 * bf2f(t3[j]);
            }
        }
        for (; p < cnt; p += 2) {
            int   s0 = __shfl(lsrc, p);
            float w0 = __shfl(lw, p);
            const ushort8* r0 = base + (size_t)s0 * HSLOTS;
            ushort8 v0 = r0[sl];
#pragma unroll
            for (int j = 0; j < 8; ++j) a[j] += w0 * bf2f(v0[j]);
            if (sl < 2) {
                ushort8 t0 = r0[32 + sl];
#pragma unroll
                for (int j = 0; j < 8; ++j) ta[j] += w0 * bf2f(t0[j]);
            }
        }
    }

    const float di = dis[i];
    if (h == 0) {   // self-loop once (halves merged below)
        const ushort8* hr = base + (size_t)i * HSLOTS;
        ushort8 v = hr[sl];
#pragma unroll
        for (int j = 0; j < 8; ++j) a[j] += di * bf2f(v[j]);
        if (sl < 2) {
            ushort8 vt = hr[32 + sl];
#pragma unroll
            for (int j = 0; j < 8; ++j) ta[j] += di * bf2f(vt[j]);
        }
    }
    // merge halves
#pragma unroll
    for (int j = 0; j < 8; ++j) a[j]  += __shfl_xor(a[j], 32);
#pragma unroll
    for (int j = 0; j < 8; ++j) ta[j] += __shfl_xor(ta[j], 32);

    float zp = 0.f;
    if (h == 0) {
        int f0 = sl * 8;
#pragma unroll
        for (int j = 0; j < 8; ++j) {
            int f = f0 + j;
            float v = fmaxf(di * a[j] + b1[f], 0.f);
            v = fmaxf((v - rm1[f]) * rsqrtf(rv1[f] + EPS) * g1[f] + beta1[f], 0.f);
            zp += v * W2[f];
        }
        if (sl < 2) {
            int ft0 = 256 + sl * 8;
#pragma unroll
            for (int j = 0; j < 8; ++j) {
                int f = ft0 + j;
                if (f < FDIM) {
                    float v = fmaxf(di * ta[j] + b1[f], 0.f);
                    v = fmaxf((v - rm1[f]) * rsqrtf(rv1[f] + EPS) * g1[f] + beta1[f], 0.f);
                    zp += v * W2[f];
                }
            }
        }
    }
#pragma unroll
    for (int off = 32; off > 0; off >>= 1) zp += __shfl_xor(zp, off);
    if (lane == 0) z[i] = zp;
}

// ---------------- agg2: pull-aggregate z + bias + bn + relu + sigmoid -> out ----------------
__global__ void agg2_kernel(const float* __restrict__ z,
                            const int* __restrict__ offs,
                            const int* __restrict__ esrc,
                            const float* __restrict__ dis,
                            const float* __restrict__ b2,
                            const float* __restrict__ g2,
                            const float* __restrict__ beta2,
                            const float* __restrict__ rm2,
                            const float* __restrict__ rv2,
                            float* __restrict__ out) {
    int i = blockIdx.x * blockDim.x + threadIdx.x;
    if (i >= N_NODES) return;
    int s = offs[i], e = offs[i + 1];
    float acc = 0.f;
    int p = s;
    for (; p + 3 < e; p += 4) {   // 4 gathers in flight
        int s0 = esrc[p], s1 = esrc[p + 1], s2 = esrc[p + 2], s3 = esrc[p + 3];
        acc += dis[s0] * z[s0] + dis[s1] * z[s1] + dis[s2] * z[s2] + dis[s3] * z[s3];
    }
    for (; p < e; ++p) {
        int s0 = esrc[p];
        acc += dis[s0] * z[s0];
    }
    float di = dis[i];
    acc += di * z[i];                 // self loop
    float pre = di * acc + b2[0];
    float v = (pre - rm2[0]) * rsqrtf(rv2[0] + EPS) * g2[0] + beta2[0];
    v = fmaxf(v, 0.f);
    out[i] = 1.f / (1.f + expf(-v));
}

// ---------------- launcher ----------------
extern "C" void kernel_launch(void* const* d_in, const int* in_sizes, int n_in,
                              void* d_out, int out_size, void* d_ws, size_t ws_size,
                              hipStream_t stream) {
    const float* x     = (const float*)d_in[0];
    const int*   ei    = (const int*)d_in[1];     // [2, E]: row = ei, col = ei + E
    const float* W1    = (const float*)d_in[2];
    const float* b1    = (const float*)d_in[3];
    const float* g1    = (const float*)d_in[4];
    const float* beta1 = (const float*)d_in[5];
    const float* rm1   = (const float*)d_in[6];
    const float* rv1   = (const float*)d_in[7];
    const float* W2    = (const float*)d_in[8];
    const float* b2    = (const float*)d_in[9];
    const float* g2    = (const float*)d_in[10];
    const float* beta2 = (const float*)d_in[11];
    const float* rm2   = (const float*)d_in[12];
    const float* rv2   = (const float*)d_in[13];
    float* out = (float*)d_out;

    // workspace layout (~12.9 MB)
    unsigned short* wt  = (unsigned short*)d_ws;            // NPAD*KPAD
    unsigned short* h1b = wt + (size_t)NPAD * KPAD;         // N_NODES*HPAD
    float* z    = (float*)(h1b + (size_t)N_NODES * HPAD);
    float* dis  = z + N_NODES;
    int* counts = (int*)(dis + N_NODES);
    int* offs   = counts + N_NODES;
    int* cursor = offs + N_NODES + 1;
    int* esrc   = cursor + N_NODES;

    const int* row = ei;
    const int* col = ei + N_EDGES;

    hipMemsetAsync(counts, 0, N_NODES * sizeof(int), stream);

    int eb = (N_EDGES + 255) / 256;
    count_kernel<<<eb, 256, 0, stream>>>(col, counts);
    scan_kernel<<<1, 1024, 0, stream>>>(counts, offs, cursor, dis);
    fill_kernel<<<eb, 256, 0, stream>>>(row, col, cursor, esrc);

    conv_w<<<(NPAD * KPAD + 255) / 256, 256, 0, stream>>>(W1, wt);

    int nwaves = (N_NODES / 32) * 9;                 // 5625
    gemm_mfma<<<(nwaves + 3) / 4, 256, 0, stream>>>(x, wt, h1b);

    agg1_kernel<<<(N_NODES + 3) / 4, 256, 0, stream>>>(h1b, offs, esrc, dis,
                                                       b1, g1, beta1, rm1, rv1, W2, z);
    agg2_kernel<<<(N_NODES + 255) / 256, 256, 0, stream>>>(z, offs, esrc, dis,
                                                           b2, g2, beta2, rm2, rv2, out);
}

// Round 7
// 132.995 us; speedup vs baseline: 1.9606x; 1.3297x over previous
//
#include <hip/hip_runtime.h>
#include <hip/hip_bf16.h>

#define N_NODES 20000
#define N_EDGES 300000
#define FDIM    268
#define KPAD    288   // K padded to 9*32 for mfma K-loop
#define NPAD    288   // N padded to 9*32
#define HPAD    272   // h1 row stride in bf16 (34 slots * 8)
#define HSLOTS  34    // HPAD/8
#define EPS     1e-3f
#define NB_SCAN ((N_NODES + 255) / 256)   // 79

typedef __attribute__((ext_vector_type(8))) short short8;
typedef __attribute__((ext_vector_type(4))) float f32x4;
typedef __attribute__((ext_vector_type(8))) unsigned short ushort8;

__device__ inline short f2bf(float f) {
    __hip_bfloat16 b = __float2bfloat16(f);   // RNE
    return *reinterpret_cast<short*>(&b);
}
__device__ inline float bf2f(unsigned short u) {
    return __uint_as_float(((unsigned int)u) << 16);
}

// ---------------- CSR build ----------------

__global__ void count_kernel(const int* __restrict__ col, int* __restrict__ counts) {
    int e = blockIdx.x * blockDim.x + threadIdx.x;
    if (e < N_EDGES) atomicAdd(&counts[col[e]], 1);
}

// stage 1: per-block exclusive scan (256 elems/block) -> offs (no base), block sums; dis
__global__ __launch_bounds__(256) void scan1_kernel(const int* __restrict__ counts,
                                                    int* __restrict__ offs,
                                                    int* __restrict__ bsums,
                                                    float* __restrict__ dis) {
    int t = threadIdx.x;
    int i = blockIdx.x * 256 + t;
    int c = (i < N_NODES) ? counts[i] : 0;
    int lane = t & 63, w = t >> 6;
    int v = c;
#pragma unroll
    for (int off = 1; off < 64; off <<= 1) {
        int u = __shfl_up(v, off);
        if (lane >= off) v += u;
    }
    __shared__ int wsum[4];
    if (lane == 63) wsum[w] = v;
    __syncthreads();
    int wbase = 0;
#pragma unroll
    for (int k = 0; k < 4; ++k) if (k < w) wbase += wsum[k];
    int incl = v + wbase;
    if (i < N_NODES) {
        offs[i] = incl - c;                         // block-local exclusive
        dis[i]  = rsqrtf((float)(c + 1));           // +1 self-loop
    }
    if (t == 255) bsums[blockIdx.x] = incl;         // block total (padding adds 0)
}

// stage 2: scan the 79 block sums (parallel load, short serial LDS scan)
__global__ __launch_bounds__(128) void scan2_kernel(int* __restrict__ bsums,
                                                    int* __restrict__ offs) {
    __shared__ int sh[NB_SCAN];
    int t = threadIdx.x;
    if (t < NB_SCAN) sh[t] = bsums[t];
    __syncthreads();
    if (t == 0) {
        int run = 0;
        for (int k = 0; k < NB_SCAN; ++k) { int v = sh[k]; sh[k] = run; run += v; }
        offs[N_NODES] = run;                        // total (== E)
    }
    __syncthreads();
    if (t < NB_SCAN) bsums[t] = sh[t];              // now exclusive bases
}

// stage 3: add block base, init cursor
__global__ __launch_bounds__(256) void scan3_kernel(const int* __restrict__ bsums,
                                                    int* __restrict__ offs,
                                                    int* __restrict__ cursor) {
    int i = blockIdx.x * 256 + threadIdx.x;
    if (i < N_NODES) {
        int o = offs[i] + bsums[blockIdx.x];
        offs[i] = o;
        cursor[i] = o;
    }
}

__global__ void fill_kernel(const int* __restrict__ row, const int* __restrict__ col,
                            int* __restrict__ cursor, int* __restrict__ esrc) {
    int e = blockIdx.x * blockDim.x + threadIdx.x;
    if (e < N_EDGES) {
        int c = col[e];
        int p = atomicAdd(&cursor[c], 1);
        esrc[p] = row[e];
    }
}

// ---------------- W1 -> W1^T bf16, zero-padded [NPAD][KPAD] ----------------
__global__ void conv_w(const float* __restrict__ W1, unsigned short* __restrict__ wt) {
    int idx = blockIdx.x * blockDim.x + threadIdx.x;
    if (idx >= NPAD * KPAD) return;
    int n = idx / KPAD, k = idx - n * KPAD;
    float v = (n < FDIM && k < FDIM) ? W1[(size_t)k * FDIM + n] : 0.f;
    wt[idx] = (unsigned short)f2bf(v);
}

// ---------------- GEMM: h1b = bf16(x) @ bf16(W1), output bf16 [N_NODES][HPAD] ----------------
// wave computes 32x32 via 2x2 mfma_f32_16x16x32_bf16 frags; A read direct from fp32 x.
__global__ __launch_bounds__(256) void gemm_mfma(const float* __restrict__ x,
                                                 const unsigned short* __restrict__ wt,
                                                 unsigned short* __restrict__ h1b) {
    int wid = blockIdx.x * 4 + (threadIdx.x >> 6);
    int m_idx = wid / 9;                  // n fastest: 9 n-waves share the A m-strip
    int n_idx = wid - m_idx * 9;
    if (m_idx >= N_NODES / 32) return;
    int lane = threadIdx.x & 63;
    int lrow = lane & 15;
    int lkg  = lane >> 4;                 // k-group 0..3
    int m0 = m_idx * 32, n0 = n_idx * 32;

    f32x4 acc[2][2];
#pragma unroll
    for (int a = 0; a < 2; ++a)
#pragma unroll
        for (int b = 0; b < 2; ++b) acc[a][b] = (f32x4){0.f, 0.f, 0.f, 0.f};

    const float* xr0 = x + (size_t)(m0 + lrow) * FDIM;
    const float* xr1 = x + (size_t)(m0 + 16 + lrow) * FDIM;

#pragma unroll
    for (int k0 = 0; k0 < KPAD; k0 += 32) {
        const int kb = k0 + lkg * 8;
        short8 a0, a1;
#pragma unroll
        for (int j = 0; j < 8; ++j) {
            int k = kb + j;                         // k0 compile-time -> mask folds away
            float v0 = (k < FDIM) ? xr0[k] : 0.f;
            float v1 = (k < FDIM) ? xr1[k] : 0.f;
            a0[j] = f2bf(v0);
            a1[j] = f2bf(v1);
        }
        short8 b0 = *reinterpret_cast<const short8*>(wt + (size_t)(n0 + lrow) * KPAD + kb);
        short8 b1 = *reinterpret_cast<const short8*>(wt + (size_t)(n0 + 16 + lrow) * KPAD + kb);
        acc[0][0] = __builtin_amdgcn_mfma_f32_16x16x32_bf16(a0, b0, acc[0][0], 0, 0, 0);
        acc[0][1] = __builtin_amdgcn_mfma_f32_16x16x32_bf16(a0, b1, acc[0][1], 0, 0, 0);
        acc[1][0] = __builtin_amdgcn_mfma_f32_16x16x32_bf16(a1, b0, acc[1][0], 0, 0, 0);
        acc[1][1] = __builtin_amdgcn_mfma_f32_16x16x32_bf16(a1, b1, acc[1][1], 0, 0, 0);
    }

    // C/D layout: col = lane&15, row = (lane>>4)*4 + reg   [m89-verified]
#pragma unroll
    for (int mi = 0; mi < 2; ++mi)
#pragma unroll
        for (int ni = 0; ni < 2; ++ni) {
            int colg = n0 + ni * 16 + lrow;
            if (colg < HPAD) {
#pragma unroll
                for (int r = 0; r < 4; ++r) {
                    int rowg = m0 + mi * 16 + lkg * 4 + r;
                    h1b[(size_t)rowg * HPAD + colg] = (unsigned short)f2bf(acc[mi][ni][r]);
                }
            }
        }
}

// ---------------- agg1: pull-aggregate bf16 h1 + bias+relu+bn+relu + dot(W2) -> z ----------------
// one wave per node. Neighbor list pre-loaded coalesced (lane l -> edge l), (src,w)
// broadcast via shfl; half-wave (32 lanes x 16B) per row, 4 rows in flight per half.
__global__ __launch_bounds__(256) void agg1_kernel(const unsigned short* __restrict__ h1b,
                                                   const int* __restrict__ offs,
                                                   const int* __restrict__ esrc,
                                                   const float* __restrict__ dis,
                                                   const float* __restrict__ b1,
                                                   const float* __restrict__ g1,
                                                   const float* __restrict__ beta1,
                                                   const float* __restrict__ rm1,
                                                   const float* __restrict__ rv1,
                                                   const float* __restrict__ W2,
                                                   float* __restrict__ z) {
    int wave = blockIdx.x * 4 + (threadIdx.x >> 6);
    if (wave >= N_NODES) return;
    int lane = threadIdx.x & 63;
    int h  = lane >> 5;       // half 0/1
    int sl = lane & 31;       // slot 0..31 (features sl*8..sl*8+7)
    const int i = wave;

    float a[8]  = {0.f, 0.f, 0.f, 0.f, 0.f, 0.f, 0.f, 0.f};
    float ta[8] = {0.f, 0.f, 0.f, 0.f, 0.f, 0.f, 0.f, 0.f};  // tail slots 32/33 (lanes sl<2)

    const ushort8* base = reinterpret_cast<const ushort8*>(h1b);
    const int s = offs[i], e = offs[i + 1];
    const int deg = e - s;

    // chunks of <=64 edges (deg > 64 is astronomically rare but handled)
    for (int c0 = 0; c0 < deg; c0 += 64) {
        int cnt = deg - c0; if (cnt > 64) cnt = 64;
        int   lsrc = 0;
        float lw   = 0.f;
        if (lane < cnt) {
            lsrc = esrc[s + c0 + lane];    // coalesced
            lw   = dis[lsrc];
        }
        int p = h;
        // 4 rows in flight per half-wave (8 per wave)
        for (; p + 6 < cnt; p += 8) {
            int   s0 = __shfl(lsrc, p),     s1 = __shfl(lsrc, p + 2);
            int   s2 = __shfl(lsrc, p + 4), s3 = __shfl(lsrc, p + 6);
            float w0 = __shfl(lw, p),       w1 = __shfl(lw, p + 2);
            float w2 = __shfl(lw, p + 4),   w3 = __shfl(lw, p + 6);
            const ushort8* r0 = base + (size_t)s0 * HSLOTS;
            const ushort8* r1 = base + (size_t)s1 * HSLOTS;
            const ushort8* r2 = base + (size_t)s2 * HSLOTS;
            const ushort8* r3 = base + (size_t)s3 * HSLOTS;
            ushort8 v0 = r0[sl], v1 = r1[sl], v2 = r2[sl], v3 = r3[sl];
#pragma unroll
            for (int j = 0; j < 8; ++j)
                a[j] += w0 * bf2f(v0[j]) + w1 * bf2f(v1[j]) + w2 * bf2f(v2[j]) + w3 * bf2f(v3[j]);
            if (sl < 2) {
                ushort8 t0 = r0[32 + sl], t1 = r1[32 + sl], t2 = r2[32 + sl], t3 = r3[32 + sl];
#pragma unroll
                for (int j = 0; j < 8; ++j)
                    ta[j] += w0 * bf2f(t0[j]) + w1 * bf2f(t1[j]) + w2 * bf2f(t2[j]) + w3 * bf2f(t3[j]);
            }
        }
        for (; p < cnt; p += 2) {
            int   s0 = __shfl(lsrc, p);
            float w0 = __shfl(lw, p);
            const ushort8* r0 = base + (size_t)s0 * HSLOTS;
            ushort8 v0 = r0[sl];
#pragma unroll
            for (int j = 0; j < 8; ++j) a[j] += w0 * bf2f(v0[j]);
            if (sl < 2) {
                ushort8 t0 = r0[32 + sl];
#pragma unroll
                for (int j = 0; j < 8; ++j) ta[j] += w0 * bf2f(t0[j]);
            }
        }
    }

    const float di = dis[i];
    if (h == 0) {   // self-loop once (halves merged below)
        const ushort8* hr = base + (size_t)i * HSLOTS;
        ushort8 v = hr[sl];
#pragma unroll
        for (int j = 0; j < 8; ++j) a[j] += di * bf2f(v[j]);
        if (sl < 2) {
            ushort8 vt = hr[32 + sl];
#pragma unroll
            for (int j = 0; j < 8; ++j) ta[j] += di * bf2f(vt[j]);
        }
    }
    // merge halves
#pragma unroll
    for (int j = 0; j < 8; ++j) a[j]  += __shfl_xor(a[j], 32);
#pragma unroll
    for (int j = 0; j < 8; ++j) ta[j] += __shfl_xor(ta[j], 32);

    float zp = 0.f;
    if (h == 0) {
        int f0 = sl * 8;
#pragma unroll
        for (int j = 0; j < 8; ++j) {
            int f = f0 + j;
            float v = fmaxf(di * a[j] + b1[f], 0.f);
            v = fmaxf((v - rm1[f]) * rsqrtf(rv1[f] + EPS) * g1[f] + beta1[f], 0.f);
            zp += v * W2[f];
        }
        if (sl < 2) {
            int ft0 = 256 + sl * 8;
#pragma unroll
            for (int j = 0; j < 8; ++j) {
                int f = ft0 + j;
                if (f < FDIM) {
                    float v = fmaxf(di * ta[j] + b1[f], 0.f);
                    v = fmaxf((v - rm1[f]) * rsqrtf(rv1[f] + EPS) * g1[f] + beta1[f], 0.f);
                    zp += v * W2[f];
                }
            }
        }
    }
#pragma unroll
    for (int off = 32; off > 0; off >>= 1) zp += __shfl_xor(zp, off);
    if (lane == 0) z[i] = zp;
}

// ---------------- agg2: pull-aggregate z + bias + bn + relu + sigmoid -> out ----------------
__global__ void agg2_kernel(const float* __restrict__ z,
                            const int* __restrict__ offs,
                            const int* __restrict__ esrc,
                            const float* __restrict__ dis,
                            const float* __restrict__ b2,
                            const float* __restrict__ g2,
                            const float* __restrict__ beta2,
                            const float* __restrict__ rm2,
                            const float* __restrict__ rv2,
                            float* __restrict__ out) {
    int i = blockIdx.x * blockDim.x + threadIdx.x;
    if (i >= N_NODES) return;
    int s = offs[i], e = offs[i + 1];
    float acc = 0.f;
    int p = s;
    for (; p + 3 < e; p += 4) {   // 4 gathers in flight
        int s0 = esrc[p], s1 = esrc[p + 1], s2 = esrc[p + 2], s3 = esrc[p + 3];
        acc += dis[s0] * z[s0] + dis[s1] * z[s1] + dis[s2] * z[s2] + dis[s3] * z[s3];
    }
    for (; p < e; ++p) {
        int s0 = esrc[p];
        acc += dis[s0] * z[s0];
    }
    float di = dis[i];
    acc += di * z[i];                 // self loop
    float pre = di * acc + b2[0];
    float v = (pre - rm2[0]) * rsqrtf(rv2[0] + EPS) * g2[0] + beta2[0];
    v = fmaxf(v, 0.f);
    out[i] = 1.f / (1.f + expf(-v));
}

// ---------------- launcher ----------------
extern "C" void kernel_launch(void* const* d_in, const int* in_sizes, int n_in,
                              void* d_out, int out_size, void* d_ws, size_t ws_size,
                              hipStream_t stream) {
    const float* x     = (const float*)d_in[0];
    const int*   ei    = (const int*)d_in[1];     // [2, E]: row = ei, col = ei + E
    const float* W1    = (const float*)d_in[2];
    const float* b1    = (const float*)d_in[3];
    const float* g1    = (const float*)d_in[4];
    const float* beta1 = (const float*)d_in[5];
    const float* rm1   = (const float*)d_in[6];
    const float* rv1   = (const float*)d_in[7];
    const float* W2    = (const float*)d_in[8];
    const float* b2    = (const float*)d_in[9];
    const float* g2    = (const float*)d_in[10];
    const float* beta2 = (const float*)d_in[11];
    const float* rm2   = (const float*)d_in[12];
    const float* rv2   = (const float*)d_in[13];
    float* out = (float*)d_out;

    // workspace layout (~12.9 MB)
    unsigned short* wt  = (unsigned short*)d_ws;            // NPAD*KPAD
    unsigned short* h1b = wt + (size_t)NPAD * KPAD;         // N_NODES*HPAD
    float* z    = (float*)(h1b + (size_t)N_NODES * HPAD);
    float* dis  = z + N_NODES;
    int* counts = (int*)(dis + N_NODES);
    int* offs   = counts + N_NODES;
    int* cursor = offs + N_NODES + 1;
    int* esrc   = cursor + N_NODES;
    int* bsums  = esrc + N_EDGES;                           // NB_SCAN

    const int* row = ei;
    const int* col = ei + N_EDGES;

    hipMemsetAsync(counts, 0, N_NODES * sizeof(int), stream);

    int eb = (N_EDGES + 255) / 256;
    count_kernel<<<eb, 256, 0, stream>>>(col, counts);
    scan1_kernel<<<NB_SCAN, 256, 0, stream>>>(counts, offs, bsums, dis);
    scan2_kernel<<<1, 128, 0, stream>>>(bsums, offs);
    scan3_kernel<<<NB_SCAN, 256, 0, stream>>>(bsums, offs, cursor);
    fill_kernel<<<eb, 256, 0, stream>>>(row, col, cursor, esrc);

    conv_w<<<(NPAD * KPAD + 255) / 256, 256, 0, stream>>>(W1, wt);

    int nwaves = (N_NODES / 32) * 9;                 // 5625
    gemm_mfma<<<(nwaves + 3) / 4, 256, 0, stream>>>(x, wt, h1b);

    agg1_kernel<<<(N_NODES + 3) / 4, 256, 0, stream>>>(h1b, offs, esrc, dis,
                                                       b1, g1, beta1, rm1, rv1, W2, z);
    agg2_kernel<<<(N_NODES + 255) / 256, 256, 0, stream>>>(z, offs, esrc, dis,
                                                           b2, g2, beta2, rm2, rv2, out);
}